// Round 2
// baseline (200.225 us; speedup 1.0000x reference)
//
#include <hip/hip_runtime.h>
#include <hip/hip_bf16.h>

// FeatureFlowAttention, local_window_attn=1, radius=1 (hard-coded per setup_inputs).
// b=4, c=128, h=w=128, hw=16384.
//
// Restructure: scores(p,p') = q_p . k_p' with q = Wq x + bq, k = Wk x + bk
//   = x_p^T M x_p' + gamma_p + delta_p' + d
// where M = Wq^T Wk, gamma_p = x_p . (Wq^T bk), delta_p' = x_p' . (Wk^T bq), d = bq.bk.
// => ONE GEMM y = M x (instead of two projections), plus per-pixel scalars.
//
// Kernel 0 (prep):  M [128x128], u, v, d
// Kernel A (proj):  y[b][ci][p] = sum_cj M[ci][cj] x[cj][p]; gamma[b][p]; delta'[b][p]=delta+d
// Kernel B (attn):  per pixel: 9 scores via dot(x_p, y_nbr) (+gamma+delta'), softmax, flow avg.

#define HW 16384
#define NB 4

__global__ void prep_kernel(const float* __restrict__ qw, const float* __restrict__ qb,
                            const float* __restrict__ kw, const float* __restrict__ kb,
                            float* __restrict__ M, float* __restrict__ u,
                            float* __restrict__ v, float* __restrict__ dptr) {
    int bid = blockIdx.x;
    int t = threadIdx.x;
    if (bid < 128) {
        // M[bid][t] = sum_co Wq[co][bid] * Wk[co][t]
        float acc = 0.f;
        for (int co = 0; co < 128; ++co)
            acc += qw[co * 128 + bid] * kw[co * 128 + t];
        M[bid * 128 + t] = acc;
    } else {
        float uu = 0.f, vv = 0.f;
        for (int co = 0; co < 128; ++co) {
            uu += qw[co * 128 + t] * kb[co];
            vv += kw[co * 128 + t] * qb[co];
        }
        u[t] = uu;
        v[t] = vv;
        if (t == 0) {
            float dd = 0.f;
            for (int co = 0; co < 128; ++co) dd += qb[co] * kb[co];
            *dptr = dd;
        }
    }
}

// Kernel A: per block, p-tile of 128 pixels, all 128 output channels.
// Thread (ty,tx), ty=tid/16, tx=tid%16: ci in {ty+16i, i=0..7}, p in {p0 + tx*4 + 64j + l}.
// 64 fp32 accumulators/thread. c chunked by 32: Flds 16 KB, Mlds stride-36 18 KB
// (36%32=4 -> read banks c+4*ty conflict-free; 16-lane broadcast per address is free).
// Total ~35 KB LDS/block.
__global__ __launch_bounds__(256, 2)
void proj_kernel(const float* __restrict__ feat, const float* __restrict__ M,
                 const float* __restrict__ u, const float* __restrict__ v,
                 const float* __restrict__ dptr, float* __restrict__ y,
                 float* __restrict__ gam, float* __restrict__ del) {
    __shared__ float Mlds[128 * 36];   // [ci][cj_chunk of 32], stride 36
    __shared__ float Flds[32 * 128];   // [c][p]
    __shared__ float ulds[32], vlds[32];

    int tid = threadIdx.x;
    int ty = tid >> 4, tx = tid & 15;
    int blk = blockIdx.x;              // b*128 + ptile
    int b = blk >> 7, pt = blk & 127;
    int p0 = pt * 128;
    const float* Fb = feat + (size_t)b * 128 * HW;

    float acc[8][8];
#pragma unroll
    for (int i = 0; i < 8; i++)
#pragma unroll
        for (int j = 0; j < 8; j++) acc[i][j] = 0.f;
    float gacc = 0.f, dacc = 0.f;

    for (int cc = 0; cc < 4; ++cc) {
        int c0 = cc * 32;
        __syncthreads();   // protect LDS from previous iteration's readers
        // stage F chunk: 32 rows x 128 px = 1024 float4
#pragma unroll
        for (int k = 0; k < 4; k++) {
            int idx = tid + 256 * k;          // 0..1023
            int c = idx >> 5, p4 = idx & 31;
            float4 f = *(const float4*)(Fb + (size_t)(c0 + c) * HW + p0 + p4 * 4);
            *(float4*)(&Flds[c * 128 + p4 * 4]) = f;
        }
        // stage M chunk: 128 rows x 32 cols = 1024 float4, stride-36 rows (16B-aligned)
#pragma unroll
        for (int k = 0; k < 4; k++) {
            int idx = tid + 256 * k;          // 0..1023
            int ci = idx >> 3, cj4 = idx & 7;
            float4 mv = *(const float4*)(M + ci * 128 + c0 + cj4 * 4);
            *(float4*)(&Mlds[ci * 36 + cj4 * 4]) = mv;
        }
        if (tid < 32) ulds[tid] = u[c0 + tid];
        else if (tid < 64) vlds[tid - 32] = v[c0 + tid - 32];
        __syncthreads();

        for (int c = 0; c < 32; ++c) {
            float4 fa = *(const float4*)(&Flds[c * 128 + tx * 4]);
            float4 fb4 = *(const float4*)(&Flds[c * 128 + 64 + tx * 4]);
#pragma unroll
            for (int i = 0; i < 8; i++) {
                float m = Mlds[(ty + 16 * i) * 36 + c];
                acc[i][0] += m * fa.x;  acc[i][1] += m * fa.y;
                acc[i][2] += m * fa.z;  acc[i][3] += m * fa.w;
                acc[i][4] += m * fb4.x; acc[i][5] += m * fb4.y;
                acc[i][6] += m * fb4.z; acc[i][7] += m * fb4.w;
            }
        }
        // gamma/delta partials: first 128 threads, pixel = tid (consecutive -> conflict-free)
        if (tid < 128) {
            for (int c = 0; c < 32; ++c) {
                float xv = Flds[c * 128 + tid];
                gacc += xv * ulds[c];
                dacc += xv * vlds[c];
            }
        }
    }

    // store y (float4, coalesced within tx groups)
#pragma unroll
    for (int i = 0; i < 8; i++) {
        float* yp = y + (size_t)(b * 128 + ty + 16 * i) * HW + p0 + tx * 4;
        *(float4*)yp = make_float4(acc[i][0], acc[i][1], acc[i][2], acc[i][3]);
        *(float4*)(yp + 64) = make_float4(acc[i][4], acc[i][5], acc[i][6], acc[i][7]);
    }
    if (tid < 128) {
        gam[(size_t)b * HW + p0 + tid] = gacc;
        del[(size_t)b * HW + p0 + tid] = dacc + *dptr;   // fold d into delta'
    }
}

// Kernel B: block = 64x4 pixel tile (wave = one 64-wide row), thread = 1 pixel.
// y-halo (6 rows x 66 cols) staged in LDS in 32-channel chunks, zero-filled OOB.
// x for own pixel in registers (coalesced global loads). OOB neighbor -> score exactly 0
// (reference's zero-padded unfold applies to the k-map), still participates in softmax.
__global__ __launch_bounds__(256, 2)
void attn_kernel(const float* __restrict__ feat, const float* __restrict__ flow,
                 const float* __restrict__ y, const float* __restrict__ gam,
                 const float* __restrict__ del, float* __restrict__ out) {
    __shared__ float ylds[32][6][68];
    __shared__ float dlds[6][68];

    int tid = threadIdx.x;
    int ty = tid >> 6, tx = tid & 63;      // ty 0..3 (wave id), tx lane
    int blk = blockIdx.x;                  // b*64 + rt*2 + ct
    int b = blk >> 6, rem = blk & 63;
    int rt = rem >> 1, ct = rem & 1;
    int y0 = rt * 4, x0 = ct * 64;

    const float* Fb = feat + (size_t)b * 128 * HW;
    const float* Yb = y + (size_t)b * 128 * HW;

    // delta' halo (rows y0-1..y0+4, cols x0-1..x0+64)
    for (int i = tid; i < 6 * 66; i += 256) {
        int r = i / 66, ccl = i - r * 66;
        int gr = y0 - 1 + r, gc = x0 - 1 + ccl;
        float val = 0.f;
        if (gr >= 0 && gr < 128 && gc >= 0 && gc < 128)
            val = del[(size_t)b * HW + gr * 128 + gc];
        dlds[r][ccl] = val;
    }

    float s[3][3] = {{0.f, 0.f, 0.f}, {0.f, 0.f, 0.f}, {0.f, 0.f, 0.f}};

    for (int cc = 0; cc < 4; ++cc) {
        int c0 = cc * 32;
        __syncthreads();   // protect ylds from previous iter's readers
        // stage y halo chunk: 32 c x 6 rows x 66 cols (runs of 66 -> coalesced)
        for (int i = tid; i < 32 * 396; i += 256) {
            int c = i / 396;
            int rr = i - c * 396;
            int r = rr / 66, ccl = rr - r * 66;
            int gr = y0 - 1 + r, gc = x0 - 1 + ccl;
            float val = 0.f;
            if (gr >= 0 && gr < 128 && gc >= 0 && gc < 128)
                val = Yb[(size_t)(c0 + c) * HW + gr * 128 + gc];
            ylds[c][r][ccl] = val;
        }
        __syncthreads();

        float xr[32];
#pragma unroll
        for (int c = 0; c < 32; c++)
            xr[c] = Fb[(size_t)(c0 + c) * HW + (y0 + ty) * 128 + x0 + tx];

#pragma unroll
        for (int c = 0; c < 32; c++) {
            float xv = xr[c];
#pragma unroll
            for (int dy = 0; dy < 3; dy++)
#pragma unroll
                for (int dx = 0; dx < 3; dx++)
                    s[dy][dx] += xv * ylds[c][ty + dy][tx + dx];
        }
    }

    int prow = y0 + ty, pcol = x0 + tx;
    int p = prow * 128 + pcol;
    float g = gam[(size_t)b * HW + p];
    const float inv = 0.08838834764831845f;   // 1/sqrt(128)

    float sc[9];
#pragma unroll
    for (int dy = 0; dy < 3; dy++)
#pragma unroll
        for (int dx = 0; dx < 3; dx++) {
            int gr = prow + dy - 1, gc = pcol + dx - 1;
            bool ib = (gr >= 0 && gr < 128 && gc >= 0 && gc < 128);
            sc[dy * 3 + dx] = ib ? (s[dy][dx] + g + dlds[ty + dy][tx + dx]) * inv : 0.f;
        }

    float m = sc[0];
#pragma unroll
    for (int k = 1; k < 9; k++) m = fmaxf(m, sc[k]);
    float e[9], sum = 0.f;
#pragma unroll
    for (int k = 0; k < 9; k++) { e[k] = __expf(sc[k] - m); sum += e[k]; }
    float rs = 1.f / sum;

    float o0 = 0.f, o1 = 0.f;
    const float* fl = flow + (size_t)b * 2 * HW;
#pragma unroll
    for (int dy = 0; dy < 3; dy++)
#pragma unroll
        for (int dx = 0; dx < 3; dx++) {
            int gr = prow + dy - 1, gc = pcol + dx - 1;
            if (gr >= 0 && gr < 128 && gc >= 0 && gc < 128) {
                float pr = e[dy * 3 + dx] * rs;
                o0 += pr * fl[gr * 128 + gc];
                o1 += pr * fl[HW + gr * 128 + gc];
            }
        }
    out[(size_t)(b * 2) * HW + p] = o0;
    out[(size_t)(b * 2 + 1) * HW + p] = o1;
}

extern "C" void kernel_launch(void* const* d_in, const int* in_sizes, int n_in,
                              void* d_out, int out_size, void* d_ws, size_t ws_size,
                              hipStream_t stream) {
    const float* feat = (const float*)d_in[0];
    const float* flow = (const float*)d_in[1];
    const float* qw = (const float*)d_in[2];
    const float* qb = (const float*)d_in[3];
    const float* kw = (const float*)d_in[4];
    const float* kb = (const float*)d_in[5];

    float* ws = (float*)d_ws;
    float* M = ws;                       // 16384
    float* u = ws + 16384;               // 128
    float* v = ws + 16512;               // 128
    float* dptr = ws + 16640;            // 1
    float* y = ws + 16896;               // 4*128*16384 = 8388608 (16B-aligned offset)
    float* gam = y + (size_t)NB * 128 * HW;   // 65536
    float* del = gam + (size_t)NB * HW;       // 65536
    float* out = (float*)d_out;

    prep_kernel<<<129, 128, 0, stream>>>(qw, qb, kw, kb, M, u, v, dptr);
    proj_kernel<<<NB * 128, 256, 0, stream>>>(feat, M, u, v, dptr, y, gam, del);
    attn_kernel<<<NB * 64, 256, 0, stream>>>(feat, flow, y, gam, del, out);
}

// Round 3
// 135.207 us; speedup vs baseline: 1.4809x; 1.4809x over previous
//
#include <hip/hip_runtime.h>

// FeatureFlowAttention (local_window_attn=1, r=1), b=4, c=128, h=w=128.
// scores(p,p') = x_p^T M x_p' + gamma_p + delta_p' + d, M = Wq^T Wk.
// Pipeline: prep (Mt,u,v,d) -> proj (y = M x, gamma, delta') ->
//           attn_partial (flat 9-shift partial scores, 4-way channel split) ->
//           attn_final (sum partials, validity-mask, softmax, flow gather).

#define HW 16384
#define NB 4
#define TOT (NB * HW)   // 65536 pixels total

// ---------------- prep: Mt[cj][ci] = sum_co qw[co][ci]*kw[co][cj]; u, v, d --------
__global__ void prep_kernel(const float* __restrict__ qw, const float* __restrict__ qb,
                            const float* __restrict__ kw, const float* __restrict__ kb,
                            float* __restrict__ Mt, float* __restrict__ u,
                            float* __restrict__ v, float* __restrict__ dptr) {
    __shared__ float sa[128];
    __shared__ float red[128];
    int bid = blockIdx.x, tid = threadIdx.x;
    if (bid < 128) {
        int ci = bid;
        if (tid < 128) sa[tid] = qw[tid * 128 + ci];   // qw column (scattered, once)
        __syncthreads();
        int col = tid & 127, h = tid >> 7;
        const float* kwp = kw + (size_t)h * 64 * 128 + col;
        float acc = 0.f;
#pragma unroll 8
        for (int j = 0; j < 64; ++j)
            acc += sa[h * 64 + j] * kwp[(size_t)j * 128];
        if (h) red[col] = acc;
        __syncthreads();
        if (!h) Mt[col * 128 + ci] = acc + red[col];   // transposed store
    } else if (bid == 128) {
        // u[t] = sum_co qw[co][t]*kb[co];  d = qb.kb
        if (tid < 128) sa[tid] = kb[tid];
        __syncthreads();
        if (tid < 128) {
            float acc = 0.f;
#pragma unroll 8
            for (int co = 0; co < 128; ++co) acc += qw[co * 128 + tid] * sa[co];
            u[tid] = acc;
            red[tid] = qb[tid] * sa[tid];
        }
        __syncthreads();
        if (tid == 0) {
            float dd = 0.f;
            for (int i = 0; i < 128; ++i) dd += red[i];
            *dptr = dd;
        }
    } else {
        // v[t] = sum_co kw[co][t]*qb[co]
        if (tid < 128) sa[tid] = qb[tid];
        __syncthreads();
        if (tid < 128) {
            float acc = 0.f;
#pragma unroll 8
            for (int co = 0; co < 128; ++co) acc += kw[co * 128 + tid] * sa[co];
            v[tid] = acc;
        }
    }
}

// ---------------- proj: y[ci][p] = sum_cj M[ci][cj] x[cj][p]; gamma; delta' ------
// Block = 64-px tile, 4 waves; lane = pixel; wave w covers ci in [w*32, w*32+32).
// M supplied as wave-uniform scalar loads (Mt rows contiguous in ci) -> FMA with
// SGPR operand: per c-iter/wave = 1 ds_read_b32 + 32 v_fmac -> VALU-bound.
__global__ __launch_bounds__(256, 4)
void proj_kernel(const float* __restrict__ feat, const float* __restrict__ Mt,
                 const float* __restrict__ u, const float* __restrict__ v,
                 const float* __restrict__ dptr, float* __restrict__ y,
                 float* __restrict__ gam, float* __restrict__ del) {
    __shared__ float F[128][64];          // [c][px], lane reads 2-way alias = free
    __shared__ float gred[4][64], dred[4][64];

    int tid = threadIdx.x;
    int blk = blockIdx.x;                 // b*256 + ptile
    int b = blk >> 8, pt = blk & 255;
    int p0 = pt * 64;
    const float* Fb = feat + (size_t)b * 128 * HW + p0;

    // stage x tile: 128 c x 64 px = 2048 float4
#pragma unroll
    for (int k = 0; k < 8; ++k) {
        int idx = tid + 256 * k;          // 0..2047
        int c = idx >> 4, q = idx & 15;
        *(float4*)&F[c][q * 4] = *(const float4*)(Fb + (size_t)c * HW + q * 4);
    }
    __syncthreads();

    int lane = tid & 63;
    // gamma/delta partials (4-way c-split across thread groups)
    {
        int cq = tid >> 6;
        float g = 0.f, dd = 0.f;
#pragma unroll 8
        for (int j = 0; j < 32; ++j) {
            float xv = F[cq * 32 + j][lane];
            g += xv * u[cq * 32 + j];
            dd += xv * v[cq * 32 + j];
        }
        gred[cq][lane] = g;
        dred[cq][lane] = dd;
    }
    __syncthreads();
    if (tid < 64) {
        float g = gred[0][tid] + gred[1][tid] + gred[2][tid] + gred[3][tid];
        float dd = dred[0][tid] + dred[1][tid] + dred[2][tid] + dred[3][tid] + *dptr;
        gam[(size_t)b * HW + p0 + tid] = g;
        del[(size_t)b * HW + p0 + tid] = dd;
    }

    // main GEMM: wave-uniform M pointer -> scalar loads
    int wci = __builtin_amdgcn_readfirstlane((tid >> 6) * 32);
    const float* __restrict__ mrow = Mt + wci;   // Mt[c][wci..wci+31] contiguous
    float acc[32];
#pragma unroll
    for (int i = 0; i < 32; ++i) acc[i] = 0.f;
#pragma unroll 2
    for (int c = 0; c < 128; ++c) {
        float xv = F[c][lane];
#pragma unroll
        for (int i = 0; i < 32; ++i)
            acc[i] = fmaf(mrow[c * 128 + i], xv, acc[i]);
    }
    float* yp = y + ((size_t)b * 128 + wci) * HW + p0 + lane;
#pragma unroll
    for (int i = 0; i < 32; ++i) yp[(size_t)i * HW] = acc[i];
}

// ---------------- attn_partial: flat 9-shift partial scores, 4-way channel split --
// Thread = 2 adjacent pixels (even P). All loads coalesced float2; row-edge
// wrap-around garbage is discarded in attn_final by index validity. No LDS.
__global__ __launch_bounds__(256, 8)
void attn_partial_kernel(const float* __restrict__ feat, const float* __restrict__ y,
                         float* __restrict__ ps) {
    int tid = threadIdx.x;
    int blk = blockIdx.x;                 // cg*128 + tileblock
    int cg = blk >> 7;
    int pp = (blk & 127) * 256 + tid;     // pixel-pair index 0..32767
    int P = pp * 2;                       // flat pixel (b*HW+p), even
    int b = P >> 14;
    int p = P & (HW - 1);
    const float* xb = feat + ((size_t)b * 128 + cg * 32) * HW + p;
    const float* yb = y + ((size_t)b * 128 + cg * 32) * HW + p;

    float s0[9], s1[9];
#pragma unroll
    for (int k = 0; k < 9; ++k) { s0[k] = 0.f; s1[k] = 0.f; }

#pragma unroll 2
    for (int c = 0; c < 32; ++c) {
        float2 xv = *(const float2*)(xb + (size_t)c * HW);
        const float* yc = yb + (size_t)c * HW;
#pragma unroll
        for (int dy = 0; dy < 3; ++dy) {
            const float* yr = yc + (dy - 1) * 128;
            float2 a  = *(const float2*)(yr - 2);   // cols p-2,p-1
            float2 bb = *(const float2*)(yr);       // cols p,  p+1
            float2 cc = *(const float2*)(yr + 2);   // cols p+2,p+3
            s0[dy * 3 + 0] += xv.x * a.y;   s1[dy * 3 + 0] += xv.y * bb.x;
            s0[dy * 3 + 1] += xv.x * bb.x;  s1[dy * 3 + 1] += xv.y * bb.y;
            s0[dy * 3 + 2] += xv.x * bb.y;  s1[dy * 3 + 2] += xv.y * cc.x;
        }
    }
    float* pso = ps + (size_t)cg * 9 * TOT + P;
#pragma unroll
    for (int k = 0; k < 9; ++k)
        *(float2*)(pso + (size_t)k * TOT) = make_float2(s0[k], s1[k]);
}

// ---------------- attn_final: sum partials, mask invalid k, softmax, flow gather --
__global__ __launch_bounds__(256, 8)
void attn_final_kernel(const float* __restrict__ flow, const float* __restrict__ ps,
                       const float* __restrict__ gam, const float* __restrict__ del,
                       float* __restrict__ out) {
    int P = blockIdx.x * 256 + threadIdx.x;   // 0..65535
    int b = P >> 14, p = P & (HW - 1);
    int row = p >> 7, col = p & 127;
    const float inv = 0.08838834764831845f;   // 1/sqrt(128)

    float g = gam[P];
    float sc[9];
    float mx = -1e30f;
#pragma unroll
    for (int k = 0; k < 9; ++k) {
        int dy = k / 3 - 1, dx = (k % 3) - 1;
        bool valid = ((unsigned)(row + dy) < 128u) && ((unsigned)(col + dx) < 128u);
        float ssum = 0.f;
#pragma unroll
        for (int cg = 0; cg < 4; ++cg) ssum += ps[(size_t)(cg * 9 + k) * TOT + P];
        int nidx = P + dy * 128 + dx;
        nidx = max(0, min(TOT - 1, nidx));    // clamp (value unused when invalid)
        float s = valid ? (ssum + g + del[nidx]) * inv : 0.f;
        sc[k] = s;
        mx = fmaxf(mx, s);
    }
    float e[9], sum = 0.f;
#pragma unroll
    for (int k = 0; k < 9; ++k) { e[k] = __expf(sc[k] - mx); sum += e[k]; }
    float rs = 1.f / sum;

    float o0 = 0.f, o1 = 0.f;
#pragma unroll
    for (int k = 0; k < 9; ++k) {
        int dy = k / 3 - 1, dx = (k % 3) - 1;
        bool valid = ((unsigned)(row + dy) < 128u) && ((unsigned)(col + dx) < 128u);
        float pr = valid ? e[k] * rs : 0.f;
        int fi0 = b * 2 * HW + p + dy * 128 + dx;
        fi0 = max(0, min(2 * TOT - 1, fi0));
        int fi1 = (b * 2 + 1) * HW + p + dy * 128 + dx;
        fi1 = max(0, min(2 * TOT - 1, fi1));
        o0 += pr * flow[fi0];
        o1 += pr * flow[fi1];
    }
    out[(size_t)(b * 2) * HW + p] = o0;
    out[(size_t)(b * 2 + 1) * HW + p] = o1;
}

extern "C" void kernel_launch(void* const* d_in, const int* in_sizes, int n_in,
                              void* d_out, int out_size, void* d_ws, size_t ws_size,
                              hipStream_t stream) {
    const float* feat = (const float*)d_in[0];
    const float* flow = (const float*)d_in[1];
    const float* qw = (const float*)d_in[2];
    const float* qb = (const float*)d_in[3];
    const float* kw = (const float*)d_in[4];
    const float* kb = (const float*)d_in[5];

    float* ws = (float*)d_ws;
    float* Mt = ws;                           // 16384
    float* u = ws + 16384;                    // 128
    float* v = ws + 16512;                    // 128
    float* dptr = ws + 16640;                 // 1 (pad to 16896)
    float* y = ws + 16896;                    // 4*128*16384 = 8388608
    float* gam = y + (size_t)NB * 128 * HW;   // 65536
    float* del = gam + (size_t)TOT;           // 65536
    float* ps = del + (size_t)TOT;            // 4*9*65536 = 2359296
    float* out = (float*)d_out;

    prep_kernel<<<130, 256, 0, stream>>>(qw, qb, kw, kb, Mt, u, v, dptr);
    proj_kernel<<<NB * 256, 256, 0, stream>>>(feat, Mt, u, v, dptr, y, gam, del);
    attn_partial_kernel<<<512, 256, 0, stream>>>(feat, y, ps);
    attn_final_kernel<<<256, 256, 0, stream>>>(flow, ps, gam, del, out);
}

// Round 5
// 127.290 us; speedup vs baseline: 1.5730x; 1.0622x over previous
//
#include <hip/hip_runtime.h>

// FeatureFlowAttention (local_window_attn=1, r=1), b=4, c=128, h=w=128.
// scores(p,p') = x_p^T M x_p' + gamma_p + delta_p' + d, M = Wq^T Wk.
// Pipeline:
//   prep:    M = Wq^T Wk split to bf16 (Mh,Ml); u, v, d.
//   proj:    y = M x via MFMA split-bf16 3-pass (mh*xh + mh*xl + ml*xh), zero LDS:
//            A-frags b128 from L2-resident Mh/Ml, B-frags built in-register from fp32 x.
//   partial: flat 9-shift partial scores (4-way channel split) + gamma/delta partials.
//   final:   sum partials, validity-mask, softmax, flow gather.

#define HW 16384
#define NB 4
#define TOT (NB * HW)   // 65536 pixels

typedef short bf16x8 __attribute__((ext_vector_type(8)));
typedef float f32x4 __attribute__((ext_vector_type(4)));

__device__ __forceinline__ unsigned short f2bf(float f) {   // RNE float->bf16
    unsigned u = __float_as_uint(f);
    return (unsigned short)((u + 0x7fffu + ((u >> 16) & 1u)) >> 16);
}
__device__ __forceinline__ float bf2f(unsigned short s) {
    return __uint_as_float(((unsigned)s) << 16);
}

// ---------------- prep ----------------------------------------------------------
__global__ void prep_kernel(const float* __restrict__ qw, const float* __restrict__ qb,
                            const float* __restrict__ kw, const float* __restrict__ kb,
                            unsigned short* __restrict__ Mh, unsigned short* __restrict__ Ml,
                            float* __restrict__ u, float* __restrict__ v,
                            float* __restrict__ dptr) {
    __shared__ float red[128];
    int bid = blockIdx.x, tid = threadIdx.x;
    if (bid < 16) {
        // M[ci][cj] = sum_co qw[co][ci] * kw[co][cj]; tile: 8 ci x 128 cj
        int ci = bid * 8 + (tid >> 5);
        int cj = (tid & 31) * 4;
        float4 acc = make_float4(0.f, 0.f, 0.f, 0.f);
#pragma unroll 4
        for (int co = 0; co < 128; ++co) {
            float qv = qw[co * 128 + ci];
            float4 kv = *(const float4*)(kw + co * 128 + cj);
            acc.x += qv * kv.x; acc.y += qv * kv.y;
            acc.z += qv * kv.z; acc.w += qv * kv.w;
        }
        int o = ci * 128 + cj;
        float a[4] = {acc.x, acc.y, acc.z, acc.w};
#pragma unroll
        for (int j = 0; j < 4; ++j) {
            unsigned short h = f2bf(a[j]);
            Mh[o + j] = h;
            Ml[o + j] = f2bf(a[j] - bf2f(h));
        }
    } else {
        // u[t] = sum qw[co][t]*kb[co];  v[t] = sum kw[co][t]*qb[co];  d = qb.kb
        int half = tid >> 7, t = tid & 127;
        const float* w  = half ? kw : qw;
        const float* bv = half ? qb : kb;
        float acc = 0.f;
#pragma unroll 4
        for (int co = 0; co < 128; ++co) acc += w[co * 128 + t] * bv[co];
        if (half) v[t] = acc; else u[t] = acc;
        if (!half) red[t] = qb[t] * kb[t];
        __syncthreads();
        if (tid == 0) {
            float dd = 0.f;
            for (int i = 0; i < 128; ++i) dd += red[i];
            *dptr = dd;
        }
    }
}

// ---------------- proj: y = M x via MFMA split-bf16, zero LDS -------------------
// Wave W: cig = W&3 (ci range cig*32..+32), pxg = W>>2 (64-px tile, within one image).
// Per 32-k chunk: A = 2 ci-tiles x {h,l} as b128 from global Mh/Ml (L2-hot);
// B = 4 px-tiles built from 8 coalesced fp32 loads + in-register bf16 split.
// Verified layouts (16x16x32 bf16): A[m=lane&15][k=(lane>>4)*8+j];
// B[k=(lane>>4)*8+j][n=lane&15]; D col=lane&15, row=(lane>>4)*4+reg.
__global__ __launch_bounds__(256, 2)
void proj_kernel(const float* __restrict__ feat, const unsigned short* __restrict__ MhG,
                 const unsigned short* __restrict__ MlG, float* __restrict__ y) {
    int tid = threadIdx.x;
    int W = blockIdx.x * 4 + (tid >> 6);
    int lane = tid & 63;
    int cig = W & 3, pxg = W >> 2;
    int ci0 = cig * 32;
    int P0 = pxg * 64;
    int b = P0 >> 14, p0 = P0 & (HW - 1);
    int m = lane & 15, q = lane >> 4;
    const float* xbase = feat + (size_t)b * 128 * HW + p0;

    f32x4 zero = {0.f, 0.f, 0.f, 0.f};
    f32x4 acc[2][4];
#pragma unroll
    for (int t = 0; t < 2; ++t)
#pragma unroll
        for (int s = 0; s < 4; ++s) acc[t][s] = zero;

#pragma unroll
    for (int kc = 0; kc < 4; ++kc) {
        int c0 = kc * 32;
        bf16x8 ah[2], al[2];
#pragma unroll
        for (int t = 0; t < 2; ++t) {
            int roff = (ci0 + t * 16 + m) * 128 + c0 + q * 8;
            ah[t] = *(const bf16x8*)(MhG + roff);
            al[t] = *(const bf16x8*)(MlG + roff);
        }
        bf16x8 bh[4], bl[4];
#pragma unroll
        for (int s = 0; s < 4; ++s) {
            const float* xp = xbase + (size_t)(c0 + q * 8) * HW + s * 16 + m;
            float xv[8];
#pragma unroll
            for (int j = 0; j < 8; ++j) xv[j] = xp[(size_t)j * HW];
#pragma unroll
            for (int j = 0; j < 8; ++j) {
                unsigned short h = f2bf(xv[j]);
                bh[s][j] = (short)h;
                bl[s][j] = (short)f2bf(xv[j] - bf2f(h));
            }
        }
#pragma unroll
        for (int t = 0; t < 2; ++t)
#pragma unroll
            for (int s = 0; s < 4; ++s) {
                acc[t][s] = __builtin_amdgcn_mfma_f32_16x16x32_bf16(ah[t], bh[s], acc[t][s], 0, 0, 0);
                acc[t][s] = __builtin_amdgcn_mfma_f32_16x16x32_bf16(ah[t], bl[s], acc[t][s], 0, 0, 0);
                acc[t][s] = __builtin_amdgcn_mfma_f32_16x16x32_bf16(al[t], bh[s], acc[t][s], 0, 0, 0);
            }
    }

    int rg = lane >> 4, col = lane & 15;
#pragma unroll
    for (int t = 0; t < 2; ++t)
#pragma unroll
        for (int s = 0; s < 4; ++s) {
            float* yp = y + ((size_t)b * 128 + ci0 + t * 16 + rg * 4) * HW + p0 + s * 16 + col;
#pragma unroll
            for (int r = 0; r < 4; ++r) yp[(size_t)r * HW] = acc[t][s][r];
        }
}

// ---------------- attn_partial: 9-shift partial scores + gamma/delta partials ----
__global__ __launch_bounds__(256, 4)
void attn_partial_kernel(const float* __restrict__ feat, const float* __restrict__ y,
                         const float* __restrict__ u, const float* __restrict__ v,
                         float* __restrict__ ps, float* __restrict__ gd) {
    int tid = threadIdx.x;
    int blk = blockIdx.x;                 // cg*128 + tileblock
    int cg = blk >> 7;
    int pp = (blk & 127) * 256 + tid;     // pixel-pair index 0..32767
    int P = pp * 2;                       // flat pixel (b*HW+p), even
    int b = P >> 14;
    int p = P & (HW - 1);
    const float* xb = feat + ((size_t)b * 128 + cg * 32) * HW + p;
    const float* yb = y + ((size_t)b * 128 + cg * 32) * HW + p;

    float s0[9], s1[9];
#pragma unroll
    for (int k = 0; k < 9; ++k) { s0[k] = 0.f; s1[k] = 0.f; }
    float g0 = 0.f, g1 = 0.f, d0 = 0.f, d1 = 0.f;

#pragma unroll 2
    for (int c = 0; c < 32; ++c) {
        float2 xv = *(const float2*)(xb + (size_t)c * HW);
        float uc = u[cg * 32 + c], vc = v[cg * 32 + c];
        g0 += xv.x * uc; g1 += xv.y * uc;
        d0 += xv.x * vc; d1 += xv.y * vc;
        const float* yc = yb + (size_t)c * HW;
#pragma unroll
        for (int dy = 0; dy < 3; ++dy) {
            const float* yr = yc + (dy - 1) * 128;
            float2 a  = *(const float2*)(yr - 2);   // cols p-2,p-1
            float2 bb = *(const float2*)(yr);       // cols p,  p+1
            float2 cc = *(const float2*)(yr + 2);   // cols p+2,p+3
            s0[dy * 3 + 0] += xv.x * a.y;   s1[dy * 3 + 0] += xv.y * bb.x;
            s0[dy * 3 + 1] += xv.x * bb.x;  s1[dy * 3 + 1] += xv.y * bb.y;
            s0[dy * 3 + 2] += xv.x * bb.y;  s1[dy * 3 + 2] += xv.y * cc.x;
        }
    }
    float* pso = ps + (size_t)cg * 9 * TOT + P;
#pragma unroll
    for (int k = 0; k < 9; ++k)
        *(float2*)(pso + (size_t)k * TOT) = make_float2(s0[k], s1[k]);
    *(float2*)(gd + (size_t)(cg * 2 + 0) * TOT + P) = make_float2(g0, g1);
    *(float2*)(gd + (size_t)(cg * 2 + 1) * TOT + P) = make_float2(d0, d1);
}

// ---------------- attn_final ----------------------------------------------------
__global__ __launch_bounds__(256, 4)
void attn_final_kernel(const float* __restrict__ flow, const float* __restrict__ ps,
                       const float* __restrict__ gd, const float* __restrict__ dptr,
                       float* __restrict__ out) {
    int P = blockIdx.x * 256 + threadIdx.x;   // 0..65535
    int b = P >> 14, p = P & (HW - 1);
    int row = p >> 7, col = p & 127;
    const float inv = 0.08838834764831845f;   // 1/sqrt(128)
    float dconst = *dptr;

    float g = 0.f;
#pragma unroll
    for (int cg = 0; cg < 4; ++cg) g += gd[(size_t)(cg * 2) * TOT + P];

    float sc[9];
    float mx = -1e30f;
#pragma unroll
    for (int k = 0; k < 9; ++k) {
        int dy = k / 3 - 1, dx = (k % 3) - 1;
        bool valid = ((unsigned)(row + dy) < 128u) && ((unsigned)(col + dx) < 128u);
        float ssum = 0.f;
#pragma unroll
        for (int cg = 0; cg < 4; ++cg) ssum += ps[(size_t)(cg * 9 + k) * TOT + P];
        int Pn = P + dy * 128 + dx;
        Pn = max(0, min(TOT - 1, Pn));
        float dsum = dconst;
#pragma unroll
        for (int cg = 0; cg < 4; ++cg) dsum += gd[(size_t)(cg * 2 + 1) * TOT + Pn];
        float s = valid ? (ssum + g + dsum) * inv : 0.f;
        sc[k] = s;
        mx = fmaxf(mx, s);
    }
    float e[9], sum = 0.f;
#pragma unroll
    for (int k = 0; k < 9; ++k) { e[k] = __expf(sc[k] - mx); sum += e[k]; }
    float rs = 1.f / sum;

    float o0 = 0.f, o1 = 0.f;
#pragma unroll
    for (int k = 0; k < 9; ++k) {
        int dy = k / 3 - 1, dx = (k % 3) - 1;
        bool valid = ((unsigned)(row + dy) < 128u) && ((unsigned)(col + dx) < 128u);
        float pr = valid ? e[k] * rs : 0.f;
        int fi0 = b * 2 * HW + p + dy * 128 + dx;
        fi0 = max(0, min(2 * TOT - 1, fi0));
        int fi1 = (b * 2 + 1) * HW + p + dy * 128 + dx;
        fi1 = max(0, min(2 * TOT - 1, fi1));
        o0 += pr * flow[fi0];
        o1 += pr * flow[fi1];
    }
    out[(size_t)(b * 2) * HW + p] = o0;
    out[(size_t)(b * 2 + 1) * HW + p] = o1;
}

extern "C" void kernel_launch(void* const* d_in, const int* in_sizes, int n_in,
                              void* d_out, int out_size, void* d_ws, size_t ws_size,
                              hipStream_t stream) {
    const float* feat = (const float*)d_in[0];
    const float* flow = (const float*)d_in[1];
    const float* qw = (const float*)d_in[2];
    const float* qb = (const float*)d_in[3];
    const float* kw = (const float*)d_in[4];
    const float* kb = (const float*)d_in[5];

    float* ws = (float*)d_ws;
    float* u = ws;                              // 128
    float* v = ws + 128;                        // 128
    float* dptr = ws + 256;                     // 1 (pad to 512)
    unsigned short* Mh = (unsigned short*)(ws + 512);    // 16384 bf16 = 8192 fl
    unsigned short* Ml = (unsigned short*)(ws + 8704);   // 16384 bf16 = 8192 fl
    float* y = ws + 16896;                      // 4*128*16384 = 8388608
    float* ps = ws + 8405760;                   // (+256 pad) 4*9*65536 = 2359296
    float* gd = ws + 10765056;                  // 4*2*65536 = 524288
    float* out = (float*)d_out;

    prep_kernel<<<17, 256, 0, stream>>>(qw, qb, kw, kb, Mh, Ml, u, v, dptr);
    proj_kernel<<<1024, 256, 0, stream>>>(feat, Mh, Ml, y);
    attn_partial_kernel<<<512, 256, 0, stream>>>(feat, y, u, v, ps, gd);
    attn_final_kernel<<<256, 256, 0, stream>>>(flow, ps, gd, dptr, out);
}